// Round 2
// baseline (1886.426 us; speedup 1.0000x reference)
//
#include <hip/hip_runtime.h>
#include <hip/hip_bf16.h>
#include <math.h>

// Problem constants (fixed-size problem)
#define NN      200000   // nodes
#define EE      600000   // directed edges
#define GG      8192     // graphs
#define DIN     64       // input dim
#define HD      128      // hidden dim
#define NL      4        // layers
#define LN_EPS  1e-5f

static constexpr int NB_SCAN = (NN + 255) / 256;   // 782 blocks for node scan

// ---------------------------------------------------------------------------
// CSR build: degree histogram -> exclusive scan -> edge fill
// ---------------------------------------------------------------------------
__global__ void hist_kernel(const int* __restrict__ dst, int* __restrict__ degi) {
    int e = blockIdx.x * 256 + threadIdx.x;
    if (e < EE) atomicAdd(&degi[dst[e]], 1);
}

__global__ void dis_kernel(const int* __restrict__ degi, float* __restrict__ dis) {
    int n = blockIdx.x * 256 + threadIdx.x;
    if (n < NN) dis[n] = rsqrtf((float)degi[n] + 1.0f);
}

__global__ void scan1_kernel(const int* __restrict__ degi, int* __restrict__ offs,
                             int* __restrict__ bsums) {
    __shared__ int s[256];
    int t = threadIdx.x;
    int i = blockIdx.x * 256 + t;
    int v = (i < NN) ? degi[i] : 0;
    s[t] = v;
    __syncthreads();
    for (int d = 1; d < 256; d <<= 1) {
        int add = (t >= d) ? s[t - d] : 0;
        __syncthreads();
        s[t] += add;
        __syncthreads();
    }
    if (i < NN) offs[i] = s[t] - v;                 // exclusive within block
    if (t == 255) bsums[blockIdx.x] = s[255];       // block total
}

__global__ void scan2_kernel(int* __restrict__ bsums) {
    __shared__ int s[1024];
    int t = threadIdx.x;
    int v = (t < NB_SCAN) ? bsums[t] : 0;
    s[t] = v;
    __syncthreads();
    for (int d = 1; d < 1024; d <<= 1) {
        int add = (t >= d) ? s[t - d] : 0;
        __syncthreads();
        s[t] += add;
        __syncthreads();
    }
    if (t < NB_SCAN) bsums[t] = s[t] - v;           // exclusive block offsets
}

__global__ void scan3_kernel(int* __restrict__ offs, const int* __restrict__ bsums,
                             int* __restrict__ cursor) {
    int i = blockIdx.x * 256 + threadIdx.x;
    if (i < NN) {
        int v = offs[i] + bsums[blockIdx.x];
        offs[i]   = v;
        cursor[i] = v;
    } else if (i == NN) {
        offs[i] = EE;
    }
}

__global__ void fill_kernel(const int* __restrict__ src, const int* __restrict__ dst,
                            int* __restrict__ cursor, int* __restrict__ csr) {
    int e = blockIdx.x * 256 + threadIdx.x;
    if (e < EE) {
        int d = dst[e];
        int p = atomicAdd(&cursor[d], 1);
        csr[p] = src[e];
    }
}

// ---------------------------------------------------------------------------
// Generic tiled f32 GEMM: C[M,128] = act( A[M,K] @ W[128,K(wstride)]^T
//                                          (+ bias) (+ Cadd) ), optional row gather on A.
// Tile: 128 rows x 128 cols, 256 threads, 8x8 register blocking, K chunked by 32.
// LDS: As 128*33*4 = 16896 B, Ws 32*132*4 = 16896 B -> 33792 B total (< 64 KiB cap).
// ---------------------------------------------------------------------------
template<int K, bool BIAS, bool ADD, bool SILU, bool GATHER>
__global__ __launch_bounds__(256, 2)
void gemm_kernel(const float* __restrict__ A, const float* __restrict__ W, int wstride,
                 const float* __restrict__ bias, const float* __restrict__ Cadd,
                 const int* __restrict__ gidx, float* __restrict__ C, int M)
{
    __shared__ float As[128][33];    // 128 rows x 32 k, pitch 33 (8*33 mod 32 = 8 -> 4 banks)
    __shared__ float Ws[32][132];    // transposed W chunk, pitch 132 (16B-aligned rows)

    const int tid = threadIdx.x;
    const int cg  = tid & 15;        // 16 col groups
    const int rg  = tid >> 4;        // 16 row groups
    const int c0  = cg * 8;
    const int m0  = blockIdx.x * 128;

    float acc[8][8];
    #pragma unroll
    for (int i = 0; i < 8; ++i)
        #pragma unroll
        for (int j = 0; j < 8; ++j) acc[i][j] = 0.f;

    for (int kc = 0; kc < K; kc += 32) {
        // stage A chunk: 128 rows x 32 k (float4 loads, 1024 loads / 256 threads)
        #pragma unroll
        for (int it = 0; it < 4; ++it) {
            int idx = it * 256 + tid;          // 0..1023
            int r   = idx >> 3;                // 0..127
            int k4  = (idx & 7) * 4;           // 0..28
            int m   = m0 + r;
            float4 v = make_float4(0.f, 0.f, 0.f, 0.f);
            if (m < M) {
                int row = GATHER ? gidx[m] : m;
                v = *(const float4*)(A + (size_t)row * K + kc + k4);
            }
            As[r][k4]     = v.x;
            As[r][k4 + 1] = v.y;
            As[r][k4 + 2] = v.z;
            As[r][k4 + 3] = v.w;
        }
        // stage W chunk transposed: Ws[k][c] = W[c][kc+k]
        #pragma unroll
        for (int it = 0; it < 4; ++it) {
            int idx = it * 256 + tid;
            int c   = idx >> 3;                // 0..127
            int k4  = (idx & 7) * 4;
            float4 v = *(const float4*)(W + (size_t)c * wstride + kc + k4);
            Ws[k4][c]     = v.x;
            Ws[k4 + 1][c] = v.y;
            Ws[k4 + 2][c] = v.z;
            Ws[k4 + 3][c] = v.w;
        }
        __syncthreads();

        #pragma unroll 8
        for (int kk = 0; kk < 32; ++kk) {
            float a[8];
            #pragma unroll
            for (int i = 0; i < 8; ++i) a[i] = As[rg * 8 + i][kk];
            float4 w0 = *(const float4*)&Ws[kk][c0];
            float4 w1 = *(const float4*)&Ws[kk][c0 + 4];
            float wv[8] = {w0.x, w0.y, w0.z, w0.w, w1.x, w1.y, w1.z, w1.w};
            #pragma unroll
            for (int i = 0; i < 8; ++i)
                #pragma unroll
                for (int j = 0; j < 8; ++j) acc[i][j] += a[i] * wv[j];
        }
        __syncthreads();
    }

    float bv[8];
    if (BIAS) {
        #pragma unroll
        for (int j = 0; j < 8; ++j) bv[j] = bias[c0 + j];
    }
    #pragma unroll
    for (int i = 0; i < 8; ++i) {
        int m = m0 + rg * 8 + i;
        if (m < M) {
            float o[8];
            #pragma unroll
            for (int j = 0; j < 8; ++j) {
                float v = acc[i][j];
                if (BIAS) v += bv[j];
                if (ADD)  v += Cadd[(size_t)m * HD + c0 + j];
                if (SILU) v = v / (1.f + __expf(-v));
                o[j] = v;
            }
            *(float4*)(C + (size_t)m * HD + c0)     = make_float4(o[0], o[1], o[2], o[3]);
            *(float4*)(C + (size_t)m * HD + c0 + 4) = make_float4(o[4], o[5], o[6], o[7]);
        }
    }
}

// ---------------------------------------------------------------------------
// Fused: agg = gather-sum + self-loop + bias; h += LN(silu(agg)) * g + b
// 128 threads per node, 2 nodes per 256-thread block.
// ---------------------------------------------------------------------------
__global__ __launch_bounds__(256)
void agg_ln_kernel(const float* __restrict__ hw, const float* __restrict__ dis,
                   const int* __restrict__ offs, const int* __restrict__ csr,
                   const float* __restrict__ cb, const float* __restrict__ lng,
                   const float* __restrict__ lnb, float* __restrict__ h)
{
    int tid   = threadIdx.x;
    int local = tid >> 7;         // 0 or 1: which node in block
    int f     = tid & 127;
    int n     = blockIdx.x * 2 + local;

    float dn  = dis[n];
    float acc = hw[(size_t)n * HD + f] * (dn * dn) + cb[f];
    int e0 = offs[n], e1 = offs[n + 1];
    for (int e = e0; e < e1; ++e) {
        int s = csr[e];
        acc += dis[s] * dn * hw[(size_t)s * HD + f];
    }
    // silu
    float v = acc / (1.f + __expf(-acc));

    // LayerNorm over 128 features (2 waves per node)
    float s1 = v, s2 = v * v;
    #pragma unroll
    for (int o = 32; o > 0; o >>= 1) {
        s1 += __shfl_down(s1, o);
        s2 += __shfl_down(s2, o);
    }
    __shared__ float red[8];
    int wid = tid >> 6;           // 0..3
    if ((tid & 63) == 0) { red[wid] = s1; red[4 + wid] = s2; }
    __syncthreads();
    float mu  = (red[local * 2] + red[local * 2 + 1]) * (1.f / 128.f);
    float ms  = (red[4 + local * 2] + red[4 + local * 2 + 1]) * (1.f / 128.f);
    float var = ms - mu * mu;
    float y   = (v - mu) * rsqrtf(var + LN_EPS) * lng[f] + lnb[f];
    h[(size_t)n * HD + f] += y;
}

// ---------------------------------------------------------------------------
// Graph pooling: offsets via binary search (batch_vec is sorted), then mean.
// ---------------------------------------------------------------------------
__global__ void goff_kernel(const int* __restrict__ bv, int* __restrict__ goff) {
    int g = blockIdx.x * 256 + threadIdx.x;
    if (g > GG) return;
    int lo = 0, hi = NN;
    while (lo < hi) {
        int mid = (lo + hi) >> 1;
        if (bv[mid] < g) lo = mid + 1; else hi = mid;
    }
    goff[g] = lo;
}

__global__ __launch_bounds__(128)
void pool_kernel(const float* __restrict__ h, const int* __restrict__ goff,
                 float* __restrict__ emb)
{
    int g = blockIdx.x;
    int f = threadIdx.x;
    int i0 = goff[g], i1 = goff[g + 1];
    float s = 0.f;
    for (int i = i0; i < i1; ++i) s += h[(size_t)i * HD + f];
    float c = (float)(i1 - i0);
    emb[(size_t)g * HD + f] = s / fmaxf(c, 1.f);
}

// ---------------------------------------------------------------------------
// Final: out[n] = dot(hid[n], w2) + b2   (one wave per node)
// ---------------------------------------------------------------------------
__global__ __launch_bounds__(256)
void out_kernel(const float* __restrict__ hid, const float* __restrict__ w2,
                const float* __restrict__ b2, float* __restrict__ out)
{
    int gw   = (blockIdx.x * 256 + threadIdx.x) >> 6;  // node id
    int lane = threadIdx.x & 63;
    if (gw >= NN) return;
    float s = hid[(size_t)gw * HD + lane] * w2[lane]
            + hid[(size_t)gw * HD + 64 + lane] * w2[64 + lane];
    #pragma unroll
    for (int o = 32; o > 0; o >>= 1) s += __shfl_down(s, o);
    if (lane == 0) out[gw] = s + b2[0];
}

// ---------------------------------------------------------------------------
// Launcher
// ---------------------------------------------------------------------------
extern "C" void kernel_launch(void* const* d_in, const int* in_sizes, int n_in,
                              void* d_out, int out_size, void* d_ws, size_t ws_size,
                              hipStream_t stream)
{
    const float* x        = (const float*)d_in[0];
    const int*   eidx     = (const int*)d_in[1];
    const int*   batchv   = (const int*)d_in[2];
    const float* in_w     = (const float*)d_in[3];
    const float* in_b     = (const float*)d_in[4];
    const float* conv_w   = (const float*)d_in[5];
    const float* conv_b   = (const float*)d_in[6];
    const float* ln_g     = (const float*)d_in[7];
    const float* ln_b     = (const float*)d_in[8];
    const float* phys_w1  = (const float*)d_in[9];
    const float* phys_b1  = (const float*)d_in[10];
    const float* phys_w2  = (const float*)d_in[11];
    const float* phys_b2  = (const float*)d_in[12];
    const float* head_w1  = (const float*)d_in[13];
    const float* head_b1  = (const float*)d_in[14];
    const float* head_w2  = (const float*)d_in[15];
    const float* head_b2  = (const float*)d_in[16];
    float* out = (float*)d_out;

    const int* esrc = eidx;        // edge_index[0]
    const int* edst = eidx + EE;   // edge_index[1]

    // workspace layout (~213 MB total)
    char* base = (char*)d_ws;
    size_t off = 0;
    auto alloc = [&](size_t bytes) {
        char* p = base + off;
        off = (off + bytes + 255) & ~(size_t)255;
        return p;
    };
    float* h      = (float*)alloc((size_t)NN * HD * 4);
    float* bufA   = (float*)alloc((size_t)NN * HD * 4);
    float* dis    = (float*)alloc((size_t)NN * 4);
    int*   degi   = (int*)  alloc((size_t)NN * 4);
    int*   offs   = (int*)  alloc((size_t)(NN + 1) * 4);
    int*   cursor = (int*)  alloc((size_t)NN * 4);
    int*   csr    = (int*)  alloc((size_t)EE * 4);
    float* emb    = (float*)alloc((size_t)GG * HD * 4);
    int*   goff   = (int*)  alloc((size_t)(GG + 1) * 4);
    int*   bsums  = (int*)  alloc(1024 * 4);
    (void)ws_size; (void)n_in; (void)in_sizes; (void)out_size;

    const int GB = (NN + 127) / 128;   // GEMM grid

    // --- CSR build ---
    hipMemsetAsync(degi, 0, (size_t)NN * 4, stream);
    hist_kernel<<<(EE + 255) / 256, 256, 0, stream>>>(edst, degi);
    dis_kernel<<<(NN + 255) / 256, 256, 0, stream>>>(degi, dis);
    scan1_kernel<<<NB_SCAN, 256, 0, stream>>>(degi, offs, bsums);
    scan2_kernel<<<1, 1024, 0, stream>>>(bsums);
    scan3_kernel<<<NB_SCAN, 256, 0, stream>>>(offs, bsums, cursor);
    fill_kernel<<<(EE + 255) / 256, 256, 0, stream>>>(esrc, edst, cursor, csr);

    // --- input projection: h = x @ in_w.T + in_b ---
    gemm_kernel<DIN, true, false, false, false><<<GB, 256, 0, stream>>>(
        x, in_w, DIN, in_b, nullptr, nullptr, h, NN);

    // --- GCN layers: hw = h @ conv_w[l].T ; h += LN(silu(agg(hw))) ---
    for (int l = 0; l < NL; ++l) {
        gemm_kernel<HD, false, false, false, false><<<GB, 256, 0, stream>>>(
            h, conv_w + (size_t)l * HD * HD, HD, nullptr, nullptr, nullptr, bufA, NN);
        agg_ln_kernel<<<NN / 2, 256, 0, stream>>>(
            bufA, dis, offs, csr, conv_b + l * HD, ln_g + l * HD, ln_b + l * HD, h);
    }

    // --- graph mean pooling ---
    goff_kernel<<<(GG + 256) / 256, 256, 0, stream>>>(batchv, goff);
    pool_kernel<<<GG, 128, 0, stream>>>(h, goff, emb);

    // --- phys MLP: t1 = silu(h@w1+b1) -> bufA ; h = t1@w2 + b2 + h (P, in place) ---
    gemm_kernel<HD, true, false, true, false><<<GB, 256, 0, stream>>>(
        h, phys_w1, HD, phys_b1, nullptr, nullptr, bufA, NN);
    gemm_kernel<HD, true, true, false, false><<<GB, 256, 0, stream>>>(
        bufA, phys_w2, HD, phys_b2, h, nullptr, h, NN);

    // --- head: t2 = P@W1a^T -> bufA ; h = silu(emb[batch]@W1b^T + t2 + b1) (in place) ---
    gemm_kernel<HD, false, false, false, false><<<GB, 256, 0, stream>>>(
        h, head_w1, 2 * HD, nullptr, nullptr, nullptr, bufA, NN);
    gemm_kernel<HD, true, true, true, true><<<GB, 256, 0, stream>>>(
        emb, head_w1 + HD, 2 * HD, head_b1, bufA, batchv, h, NN);

    // --- out = hid @ w2 + b2 ---
    out_kernel<<<(NN + 3) / 4, 256, 0, stream>>>(h, head_w2, head_b2, out);
}

// Round 3
// 1454.072 us; speedup vs baseline: 1.2973x; 1.2973x over previous
//
#include <hip/hip_runtime.h>
#include <hip/hip_bf16.h>
#include <math.h>

// Problem constants (fixed-size problem)
#define NN      200000   // nodes
#define EE      600000   // directed edges
#define GG      8192     // graphs
#define DIN     64       // input dim
#define HD      128      // hidden dim
#define NL      4        // layers
#define LN_EPS  1e-5f

static constexpr int NB_SCAN = (NN + 255) / 256;   // 782 blocks for node scan

typedef __attribute__((ext_vector_type(8))) short short8;   // 8 bf16 (4 VGPRs)
typedef __attribute__((ext_vector_type(4))) float floatx4;  // MFMA accumulator

// ---------------------------------------------------------------------------
// CSR build: degree histogram -> exclusive scan -> edge fill
// ---------------------------------------------------------------------------
__global__ void hist_kernel(const int* __restrict__ dst, int* __restrict__ degi) {
    int e = blockIdx.x * 256 + threadIdx.x;
    if (e < EE) atomicAdd(&degi[dst[e]], 1);
}

__global__ void dis_kernel(const int* __restrict__ degi, float* __restrict__ dis) {
    int n = blockIdx.x * 256 + threadIdx.x;
    if (n < NN) dis[n] = rsqrtf((float)degi[n] + 1.0f);
}

__global__ void scan1_kernel(const int* __restrict__ degi, int* __restrict__ offs,
                             int* __restrict__ bsums) {
    __shared__ int s[256];
    int t = threadIdx.x;
    int i = blockIdx.x * 256 + t;
    int v = (i < NN) ? degi[i] : 0;
    s[t] = v;
    __syncthreads();
    for (int d = 1; d < 256; d <<= 1) {
        int add = (t >= d) ? s[t - d] : 0;
        __syncthreads();
        s[t] += add;
        __syncthreads();
    }
    if (i < NN) offs[i] = s[t] - v;
    if (t == 255) bsums[blockIdx.x] = s[255];
}

__global__ void scan2_kernel(int* __restrict__ bsums) {
    __shared__ int s[1024];
    int t = threadIdx.x;
    int v = (t < NB_SCAN) ? bsums[t] : 0;
    s[t] = v;
    __syncthreads();
    for (int d = 1; d < 1024; d <<= 1) {
        int add = (t >= d) ? s[t - d] : 0;
        __syncthreads();
        s[t] += add;
        __syncthreads();
    }
    if (t < NB_SCAN) bsums[t] = s[t] - v;
}

__global__ void scan3_kernel(int* __restrict__ offs, const int* __restrict__ bsums,
                             int* __restrict__ cursor) {
    int i = blockIdx.x * 256 + threadIdx.x;
    if (i < NN) {
        int v = offs[i] + bsums[blockIdx.x];
        offs[i]   = v;
        cursor[i] = v;
    } else if (i == NN) {
        offs[i] = EE;
    }
}

__global__ void fill_kernel(const int* __restrict__ src, const int* __restrict__ dst,
                            int* __restrict__ cursor, int* __restrict__ csr) {
    int e = blockIdx.x * 256 + threadIdx.x;
    if (e < EE) {
        int d = dst[e];
        int p = atomicAdd(&cursor[d], 1);
        csr[p] = src[e];
    }
}

// ---------------------------------------------------------------------------
// Weight conversion f32 -> bf16 (strided rows)
// ---------------------------------------------------------------------------
__global__ void cvt_kernel(const float* __restrict__ src, __hip_bfloat16* __restrict__ dst,
                           int rows, int rlen, int sstride) {
    int idx = blockIdx.x * 256 + threadIdx.x;
    if (idx >= rows * rlen) return;
    int r = idx / rlen, c = idx - r * rlen;
    dst[idx] = __float2bfloat16(src[(size_t)r * sstride + c]);
}

// ---------------------------------------------------------------------------
// bf16 MFMA GEMM: C[M,128] = act( A[M,K] @ W[128,K]^T (+bias) (+Cadd) )
// A: bf16 (or f32 converted on the fly). W: bf16 contiguous [128][K].
// Tile 128x128, 256 threads (4 waves), wave tile 64x64 (4x4 of 16x16x32 MFMA).
// LDS: As[128][72] + Ws[128][72] shorts = 36864 B.
// ADDT: 0 none, 1 f32, 2 bf16.  Output: f32 Cf and/or bf16 Cb.
// ---------------------------------------------------------------------------
template<int K, bool AF32, bool GATHER, bool BIAS, int ADDT, bool SILU, bool WF32, bool WBF>
__global__ __launch_bounds__(256, 2)
void mgemm(const void* __restrict__ Avp, const __hip_bfloat16* __restrict__ W,
           const float* __restrict__ bias, const void* __restrict__ Caddvp,
           const int* __restrict__ gidx,
           float* __restrict__ Cf, __hip_bfloat16* __restrict__ Cb, int M)
{
    constexpr int AP = 72;               // LDS row pitch in shorts (64 + 8 pad)
    __shared__ short As[128 * AP];
    __shared__ short Ws[128 * AP];

    const int tid  = threadIdx.x;
    const int wave = tid >> 6;
    const int lane = tid & 63;
    const int l15  = lane & 15;
    const int quad = lane >> 4;          // 0..3
    const int wm   = (wave >> 1) * 64;   // wave row offset in tile
    const int wn   = (wave & 1) * 64;    // wave col offset in tile
    const int m0   = blockIdx.x * 128;

    floatx4 acc[4][4];
    #pragma unroll
    for (int i = 0; i < 4; ++i)
        #pragma unroll
        for (int j = 0; j < 4; ++j) acc[i][j] = (floatx4)0.f;

    const float* Af          = (const float*)Avp;
    const __hip_bfloat16* Ab = (const __hip_bfloat16*)Avp;

    for (int kc = 0; kc < K; kc += 64) {
        // stage A: 128 rows x 64 k, 8 elems (16 B bf16) per thread per pass
        #pragma unroll
        for (int it = 0; it < 4; ++it) {
            int idx = it * 256 + tid;        // 0..1023
            int r   = idx >> 3;              // 0..127
            int c8  = (idx & 7) * 8;         // 0..56
            int m   = m0 + r;
            short8 v = (short8)0;
            if (m < M) {
                int row = GATHER ? gidx[m] : m;
                if (AF32) {
                    const float* p = Af + (size_t)row * K + kc + c8;
                    float4 x0 = *(const float4*)p;
                    float4 x1 = *(const float4*)(p + 4);
                    float xv[8] = {x0.x, x0.y, x0.z, x0.w, x1.x, x1.y, x1.z, x1.w};
                    #pragma unroll
                    for (int j = 0; j < 8; ++j) {
                        __hip_bfloat16 t = __float2bfloat16(xv[j]);
                        v[j] = *reinterpret_cast<short*>(&t);
                    }
                } else {
                    v = *(const short8*)(Ab + (size_t)row * K + kc + c8);
                }
            }
            *(short8*)&As[r * AP + c8] = v;
        }
        // stage W: 128 rows x 64 k
        #pragma unroll
        for (int it = 0; it < 4; ++it) {
            int idx = it * 256 + tid;
            int c   = idx >> 3;
            int c8  = (idx & 7) * 8;
            short8 v = *(const short8*)(W + (size_t)c * K + kc + c8);
            *(short8*)&Ws[c * AP + c8] = v;
        }
        __syncthreads();

        #pragma unroll
        for (int ks = 0; ks < 2; ++ks) {
            int kk = ks * 32 + quad * 8;
            short8 a[4], b[4];
            #pragma unroll
            for (int mi = 0; mi < 4; ++mi)
                a[mi] = *(const short8*)&As[(wm + mi * 16 + l15) * AP + kk];
            #pragma unroll
            for (int ni = 0; ni < 4; ++ni)
                b[ni] = *(const short8*)&Ws[(wn + ni * 16 + l15) * AP + kk];
            #pragma unroll
            for (int mi = 0; mi < 4; ++mi)
                #pragma unroll
                for (int ni = 0; ni < 4; ++ni)
                    acc[mi][ni] = __builtin_amdgcn_mfma_f32_16x16x32_bf16(
                        a[mi], b[ni], acc[mi][ni], 0, 0, 0);
        }
        __syncthreads();
    }

    // epilogue: D row = wm + mi*16 + quad*4 + r, col = wn + ni*16 + l15
    float bv[4];
    if (BIAS) {
        #pragma unroll
        for (int ni = 0; ni < 4; ++ni) bv[ni] = bias[wn + ni * 16 + l15];
    }
    const float* Caf          = (const float*)Caddvp;
    const __hip_bfloat16* Cab = (const __hip_bfloat16*)Caddvp;
    #pragma unroll
    for (int mi = 0; mi < 4; ++mi) {
        #pragma unroll
        for (int r = 0; r < 4; ++r) {
            int m = m0 + wm + mi * 16 + quad * 4 + r;
            if (m < M) {
                #pragma unroll
                for (int ni = 0; ni < 4; ++ni) {
                    int n = wn + ni * 16 + l15;
                    float v = acc[mi][ni][r];
                    if (BIAS) v += bv[ni];
                    if (ADDT == 1) v += Caf[(size_t)m * HD + n];
                    if (ADDT == 2) v += __bfloat162float(Cab[(size_t)m * HD + n]);
                    if (SILU) v = v / (1.f + __expf(-v));
                    if (WF32) Cf[(size_t)m * HD + n] = v;
                    if (WBF)  Cb[(size_t)m * HD + n] = __float2bfloat16(v);
                }
            }
        }
    }
}

// ---------------------------------------------------------------------------
// Fused: agg = gather-sum(bf16 hw) + self-loop + bias; h += LN(silu(agg));
// also emits bf16 mirror of updated h. 128 threads/node, 2 nodes/block.
// ---------------------------------------------------------------------------
__global__ __launch_bounds__(256)
void agg_ln_kernel(const __hip_bfloat16* __restrict__ hw, const float* __restrict__ dis,
                   const int* __restrict__ offs, const int* __restrict__ csr,
                   const float* __restrict__ cb, const float* __restrict__ lng,
                   const float* __restrict__ lnb, float* __restrict__ h,
                   __hip_bfloat16* __restrict__ hbf)
{
    int tid   = threadIdx.x;
    int local = tid >> 7;
    int f     = tid & 127;
    int n     = blockIdx.x * 2 + local;

    float dn  = dis[n];
    float acc = __bfloat162float(hw[(size_t)n * HD + f]) * (dn * dn) + cb[f];
    int e0 = offs[n], e1 = offs[n + 1];
    for (int e = e0; e < e1; ++e) {
        int s = csr[e];
        acc += dis[s] * dn * __bfloat162float(hw[(size_t)s * HD + f]);
    }
    float v = acc / (1.f + __expf(-acc));

    float s1 = v, s2 = v * v;
    #pragma unroll
    for (int o = 32; o > 0; o >>= 1) {
        s1 += __shfl_down(s1, o);
        s2 += __shfl_down(s2, o);
    }
    __shared__ float red[8];
    int wid = tid >> 6;
    if ((tid & 63) == 0) { red[wid] = s1; red[4 + wid] = s2; }
    __syncthreads();
    float mu  = (red[local * 2] + red[local * 2 + 1]) * (1.f / 128.f);
    float ms  = (red[4 + local * 2] + red[4 + local * 2 + 1]) * (1.f / 128.f);
    float var = ms - mu * mu;
    float y   = (v - mu) * rsqrtf(var + LN_EPS) * lng[f] + lnb[f];
    float hn  = h[(size_t)n * HD + f] + y;
    h[(size_t)n * HD + f]   = hn;
    hbf[(size_t)n * HD + f] = __float2bfloat16(hn);
}

// ---------------------------------------------------------------------------
// Graph pooling: offsets via binary search (batch_vec sorted), then mean -> bf16.
// ---------------------------------------------------------------------------
__global__ void goff_kernel(const int* __restrict__ bv, int* __restrict__ goff) {
    int g = blockIdx.x * 256 + threadIdx.x;
    if (g > GG) return;
    int lo = 0, hi = NN;
    while (lo < hi) {
        int mid = (lo + hi) >> 1;
        if (bv[mid] < g) lo = mid + 1; else hi = mid;
    }
    goff[g] = lo;
}

__global__ __launch_bounds__(128)
void pool_kernel(const float* __restrict__ h, const int* __restrict__ goff,
                 __hip_bfloat16* __restrict__ emb)
{
    int g = blockIdx.x;
    int f = threadIdx.x;
    int i0 = goff[g], i1 = goff[g + 1];
    float s = 0.f;
    for (int i = i0; i < i1; ++i) s += h[(size_t)i * HD + f];
    float c = (float)(i1 - i0);
    emb[(size_t)g * HD + f] = __float2bfloat16(s / fmaxf(c, 1.f));
}

// ---------------------------------------------------------------------------
// Final: out[n] = dot(hid[n], w2) + b2   (one wave per node, hid in bf16)
// ---------------------------------------------------------------------------
__global__ __launch_bounds__(256)
void out_kernel(const __hip_bfloat16* __restrict__ hid, const float* __restrict__ w2,
                const float* __restrict__ b2, float* __restrict__ out)
{
    int gw   = (blockIdx.x * 256 + threadIdx.x) >> 6;
    int lane = threadIdx.x & 63;
    if (gw >= NN) return;
    float s = __bfloat162float(hid[(size_t)gw * HD + lane]) * w2[lane]
            + __bfloat162float(hid[(size_t)gw * HD + 64 + lane]) * w2[64 + lane];
    #pragma unroll
    for (int o = 32; o > 0; o >>= 1) s += __shfl_down(s, o);
    if (lane == 0) out[gw] = s + b2[0];
}

// ---------------------------------------------------------------------------
// Launcher
// ---------------------------------------------------------------------------
extern "C" void kernel_launch(void* const* d_in, const int* in_sizes, int n_in,
                              void* d_out, int out_size, void* d_ws, size_t ws_size,
                              hipStream_t stream)
{
    const float* x        = (const float*)d_in[0];
    const int*   eidx     = (const int*)d_in[1];
    const int*   batchv   = (const int*)d_in[2];
    const float* in_w     = (const float*)d_in[3];
    const float* in_b     = (const float*)d_in[4];
    const float* conv_w   = (const float*)d_in[5];
    const float* conv_b   = (const float*)d_in[6];
    const float* ln_g     = (const float*)d_in[7];
    const float* ln_b     = (const float*)d_in[8];
    const float* phys_w1  = (const float*)d_in[9];
    const float* phys_b1  = (const float*)d_in[10];
    const float* phys_w2  = (const float*)d_in[11];
    const float* phys_b2  = (const float*)d_in[12];
    const float* head_w1  = (const float*)d_in[13];
    const float* head_b1  = (const float*)d_in[14];
    const float* head_w2  = (const float*)d_in[15];
    const float* head_b2  = (const float*)d_in[16];
    float* out = (float*)d_out;

    const int* esrc = eidx;
    const int* edst = eidx + EE;

    // workspace layout (~215 MB total)
    char* base = (char*)d_ws;
    size_t off = 0;
    auto alloc = [&](size_t bytes) {
        char* p = base + off;
        off = (off + bytes + 255) & ~(size_t)255;
        return p;
    };
    float*          h      = (float*)alloc((size_t)NN * HD * 4);
    __hip_bfloat16* hbf    = (__hip_bfloat16*)alloc((size_t)NN * HD * 2);
    __hip_bfloat16* bufA   = (__hip_bfloat16*)alloc((size_t)NN * HD * 2);
    float*          dis    = (float*)alloc((size_t)NN * 4);
    int*            degi   = (int*)  alloc((size_t)NN * 4);
    int*            offs   = (int*)  alloc((size_t)(NN + 1) * 4);
    int*            cursor = (int*)  alloc((size_t)NN * 4);
    int*            csr    = (int*)  alloc((size_t)EE * 4);
    __hip_bfloat16* emb    = (__hip_bfloat16*)alloc((size_t)GG * HD * 2);
    int*            goff   = (int*)  alloc((size_t)(GG + 1) * 4);
    int*            bsums  = (int*)  alloc(1024 * 4);
    __hip_bfloat16* w_in   = (__hip_bfloat16*)alloc(HD * DIN * 2);
    __hip_bfloat16* w_conv = (__hip_bfloat16*)alloc((size_t)NL * HD * HD * 2);
    __hip_bfloat16* w_p1   = (__hip_bfloat16*)alloc(HD * HD * 2);
    __hip_bfloat16* w_p2   = (__hip_bfloat16*)alloc(HD * HD * 2);
    __hip_bfloat16* w_h1a  = (__hip_bfloat16*)alloc(HD * HD * 2);
    __hip_bfloat16* w_h1b  = (__hip_bfloat16*)alloc(HD * HD * 2);
    (void)ws_size; (void)n_in; (void)in_sizes; (void)out_size;

    const int GB = (NN + 127) / 128;   // GEMM grid

    // --- weight conversion (tiny) ---
    cvt_kernel<<<(HD * DIN + 255) / 256, 256, 0, stream>>>(in_w, w_in, HD, DIN, DIN);
    cvt_kernel<<<(NL * HD * HD + 255) / 256, 256, 0, stream>>>(conv_w, w_conv, NL * HD, HD, HD);
    cvt_kernel<<<(HD * HD + 255) / 256, 256, 0, stream>>>(phys_w1, w_p1, HD, HD, HD);
    cvt_kernel<<<(HD * HD + 255) / 256, 256, 0, stream>>>(phys_w2, w_p2, HD, HD, HD);
    cvt_kernel<<<(HD * HD + 255) / 256, 256, 0, stream>>>(head_w1, w_h1a, HD, HD, 2 * HD);
    cvt_kernel<<<(HD * HD + 255) / 256, 256, 0, stream>>>(head_w1 + HD, w_h1b, HD, HD, 2 * HD);

    // --- CSR build ---
    hipMemsetAsync(degi, 0, (size_t)NN * 4, stream);
    hist_kernel<<<(EE + 255) / 256, 256, 0, stream>>>(edst, degi);
    dis_kernel<<<(NN + 255) / 256, 256, 0, stream>>>(degi, dis);
    scan1_kernel<<<NB_SCAN, 256, 0, stream>>>(degi, offs, bsums);
    scan2_kernel<<<1, 1024, 0, stream>>>(bsums);
    scan3_kernel<<<NB_SCAN, 256, 0, stream>>>(offs, bsums, cursor);
    fill_kernel<<<(EE + 255) / 256, 256, 0, stream>>>(esrc, edst, cursor, csr);

    // --- input projection: h = x @ in_w.T + in_b  (f32 A converted on the fly) ---
    mgemm<DIN, true, false, true, 0, false, true, true><<<GB, 256, 0, stream>>>(
        x, w_in, in_b, nullptr, nullptr, h, hbf, NN);

    // --- GCN layers: hw_bf = h_bf @ conv_w[l].T ; h += LN(silu(agg(hw))) ---
    for (int l = 0; l < NL; ++l) {
        mgemm<HD, false, false, false, 0, false, false, true><<<GB, 256, 0, stream>>>(
            hbf, w_conv + (size_t)l * HD * HD, nullptr, nullptr, nullptr, nullptr, bufA, NN);
        agg_ln_kernel<<<NN / 2, 256, 0, stream>>>(
            bufA, dis, offs, csr, conv_b + l * HD, ln_g + l * HD, ln_b + l * HD, h, hbf);
    }

    // --- graph mean pooling (bf16 emb) ---
    goff_kernel<<<(GG + 256) / 256, 256, 0, stream>>>(batchv, goff);
    pool_kernel<<<GG, 128, 0, stream>>>(h, goff, emb);

    // --- phys MLP: t1 = silu(h@w1+b1) -> bufA(bf16) ; h = t1@w2 + b2 + h ---
    mgemm<HD, false, false, true, 0, true, false, true><<<GB, 256, 0, stream>>>(
        hbf, w_p1, phys_b1, nullptr, nullptr, nullptr, bufA, NN);
    mgemm<HD, false, false, true, 1, false, true, true><<<GB, 256, 0, stream>>>(
        bufA, w_p2, phys_b2, h, nullptr, h, hbf, NN);

    // --- head: t2 = P@W1a^T -> bufA(bf16) ; hid = silu(emb[batch]@W1b^T + t2 + b1) -> hbf ---
    mgemm<HD, false, false, false, 0, false, false, true><<<GB, 256, 0, stream>>>(
        hbf, w_h1a, nullptr, nullptr, nullptr, nullptr, bufA, NN);
    mgemm<HD, false, true, true, 2, true, false, true><<<GB, 256, 0, stream>>>(
        emb, w_h1b, head_b1, bufA, batchv, nullptr, hbf, NN);

    // --- out = hid @ w2 + b2 ---
    out_kernel<<<(NN + 3) / 4, 256, 0, stream>>>(hbf, head_w2, head_b2, out);
}

// Round 4
// 820.098 us; speedup vs baseline: 2.3002x; 1.7730x over previous
//
#include <hip/hip_runtime.h>
#include <hip/hip_bf16.h>
#include <math.h>

// Problem constants (fixed-size problem)
#define NN      200000   // nodes
#define EE      600000   // directed edges
#define GG      8192     // graphs
#define DIN     64       // input dim
#define HD      128      // hidden dim
#define NL      4        // layers
#define LN_EPS  1e-5f

static constexpr int NB_SCAN = (NN + 255) / 256;   // 782 blocks for node scan

typedef __attribute__((ext_vector_type(8))) short short8;   // 8 bf16 (4 VGPRs)
typedef __attribute__((ext_vector_type(4))) float floatx4;  // MFMA accumulator

// bf16x2 <-> float2 (exact: bf16->f32 is a 16-bit shift)
__device__ inline float2 unpack_bf2(unsigned int p) {
    return make_float2(__uint_as_float(p << 16), __uint_as_float(p & 0xffff0000u));
}
__device__ inline unsigned int pack_bf2(float a, float b) {
    __hip_bfloat16 lo = __float2bfloat16(a);
    __hip_bfloat16 hi = __float2bfloat16(b);
    unsigned short ul = *reinterpret_cast<unsigned short*>(&lo);
    unsigned short uh = *reinterpret_cast<unsigned short*>(&hi);
    return (unsigned int)ul | ((unsigned int)uh << 16);
}

// ---------------------------------------------------------------------------
// CSR build: degree histogram -> exclusive scan -> edge fill (with edge norm)
// ---------------------------------------------------------------------------
__global__ void hist_kernel(const int* __restrict__ dst, int* __restrict__ degi) {
    int e = blockIdx.x * 256 + threadIdx.x;
    if (e < EE) atomicAdd(&degi[dst[e]], 1);
}

__global__ void dis_kernel(const int* __restrict__ degi, float* __restrict__ dis) {
    int n = blockIdx.x * 256 + threadIdx.x;
    if (n < NN) dis[n] = rsqrtf((float)degi[n] + 1.0f);
}

__global__ void scan1_kernel(const int* __restrict__ degi, int* __restrict__ offs,
                             int* __restrict__ bsums) {
    __shared__ int s[256];
    int t = threadIdx.x;
    int i = blockIdx.x * 256 + t;
    int v = (i < NN) ? degi[i] : 0;
    s[t] = v;
    __syncthreads();
    for (int d = 1; d < 256; d <<= 1) {
        int add = (t >= d) ? s[t - d] : 0;
        __syncthreads();
        s[t] += add;
        __syncthreads();
    }
    if (i < NN) offs[i] = s[t] - v;
    if (t == 255) bsums[blockIdx.x] = s[255];
}

__global__ void scan2_kernel(int* __restrict__ bsums) {
    __shared__ int s[1024];
    int t = threadIdx.x;
    int v = (t < NB_SCAN) ? bsums[t] : 0;
    s[t] = v;
    __syncthreads();
    for (int d = 1; d < 1024; d <<= 1) {
        int add = (t >= d) ? s[t - d] : 0;
        __syncthreads();
        s[t] += add;
        __syncthreads();
    }
    if (t < NB_SCAN) bsums[t] = s[t] - v;
}

__global__ void scan3_kernel(int* __restrict__ offs, const int* __restrict__ bsums,
                             int* __restrict__ cursor) {
    int i = blockIdx.x * 256 + threadIdx.x;
    if (i < NN) {
        int v = offs[i] + bsums[blockIdx.x];
        offs[i]   = v;
        cursor[i] = v;
    } else if (i == NN) {
        offs[i] = EE;
    }
}

// csre[p] = {src, dis[src]*dis[dst]} -- per-edge norm precomputed
__global__ void fill_kernel(const int* __restrict__ src, const int* __restrict__ dst,
                            const float* __restrict__ dis,
                            int* __restrict__ cursor, int2* __restrict__ csre) {
    int e = blockIdx.x * 256 + threadIdx.x;
    if (e < EE) {
        int s = src[e], d = dst[e];
        int p = atomicAdd(&cursor[d], 1);
        csre[p] = make_int2(s, __float_as_int(dis[s] * dis[d]));
    }
}

// ---------------------------------------------------------------------------
// Weight conversion f32 -> bf16 (strided rows)
// ---------------------------------------------------------------------------
__global__ void cvt_kernel(const float* __restrict__ src, __hip_bfloat16* __restrict__ dst,
                           int rows, int rlen, int sstride) {
    int idx = blockIdx.x * 256 + threadIdx.x;
    if (idx >= rows * rlen) return;
    int r = idx / rlen, c = idx - r * rlen;
    dst[idx] = __float2bfloat16(src[(size_t)r * sstride + c]);
}

// ---------------------------------------------------------------------------
// bf16 MFMA GEMM: C[M,128] = act( A[M,K] @ W[128,K]^T (+bias) (+Cadd) )
// Tile 128x128, 256 threads (4 waves), wave tile 64x64 (4x4 of 16x16x32 MFMA).
// ---------------------------------------------------------------------------
template<int K, bool AF32, bool GATHER, bool BIAS, int ADDT, bool SILU, bool WF32, bool WBF>
__global__ __launch_bounds__(256, 2)
void mgemm(const void* __restrict__ Avp, const __hip_bfloat16* __restrict__ W,
           const float* __restrict__ bias, const void* __restrict__ Caddvp,
           const int* __restrict__ gidx,
           float* __restrict__ Cf, __hip_bfloat16* __restrict__ Cb, int M)
{
    constexpr int AP = 72;               // LDS row pitch in shorts (64 + 8 pad)
    __shared__ short As[128 * AP];
    __shared__ short Ws[128 * AP];

    const int tid  = threadIdx.x;
    const int wave = tid >> 6;
    const int lane = tid & 63;
    const int l15  = lane & 15;
    const int quad = lane >> 4;          // 0..3
    const int wm   = (wave >> 1) * 64;   // wave row offset in tile
    const int wn   = (wave & 1) * 64;    // wave col offset in tile
    const int m0   = blockIdx.x * 128;

    floatx4 acc[4][4];
    #pragma unroll
    for (int i = 0; i < 4; ++i)
        #pragma unroll
        for (int j = 0; j < 4; ++j) acc[i][j] = (floatx4)0.f;

    const float* Af          = (const float*)Avp;
    const __hip_bfloat16* Ab = (const __hip_bfloat16*)Avp;

    for (int kc = 0; kc < K; kc += 64) {
        #pragma unroll
        for (int it = 0; it < 4; ++it) {
            int idx = it * 256 + tid;        // 0..1023
            int r   = idx >> 3;              // 0..127
            int c8  = (idx & 7) * 8;         // 0..56
            int m   = m0 + r;
            short8 v = (short8)0;
            if (m < M) {
                int row = GATHER ? gidx[m] : m;
                if (AF32) {
                    const float* p = Af + (size_t)row * K + kc + c8;
                    float4 x0 = *(const float4*)p;
                    float4 x1 = *(const float4*)(p + 4);
                    float xv[8] = {x0.x, x0.y, x0.z, x0.w, x1.x, x1.y, x1.z, x1.w};
                    #pragma unroll
                    for (int j = 0; j < 8; ++j) {
                        __hip_bfloat16 t = __float2bfloat16(xv[j]);
                        v[j] = *reinterpret_cast<short*>(&t);
                    }
                } else {
                    v = *(const short8*)(Ab + (size_t)row * K + kc + c8);
                }
            }
            *(short8*)&As[r * AP + c8] = v;
        }
        #pragma unroll
        for (int it = 0; it < 4; ++it) {
            int idx = it * 256 + tid;
            int c   = idx >> 3;
            int c8  = (idx & 7) * 8;
            short8 v = *(const short8*)(W + (size_t)c * K + kc + c8);
            *(short8*)&Ws[c * AP + c8] = v;
        }
        __syncthreads();

        #pragma unroll
        for (int ks = 0; ks < 2; ++ks) {
            int kk = ks * 32 + quad * 8;
            short8 a[4], b[4];
            #pragma unroll
            for (int mi = 0; mi < 4; ++mi)
                a[mi] = *(const short8*)&As[(wm + mi * 16 + l15) * AP + kk];
            #pragma unroll
            for (int ni = 0; ni < 4; ++ni)
                b[ni] = *(const short8*)&Ws[(wn + ni * 16 + l15) * AP + kk];
            #pragma unroll
            for (int mi = 0; mi < 4; ++mi)
                #pragma unroll
                for (int ni = 0; ni < 4; ++ni)
                    acc[mi][ni] = __builtin_amdgcn_mfma_f32_16x16x32_bf16(
                        a[mi], b[ni], acc[mi][ni], 0, 0, 0);
        }
        __syncthreads();
    }

    float bv[4];
    if (BIAS) {
        #pragma unroll
        for (int ni = 0; ni < 4; ++ni) bv[ni] = bias[wn + ni * 16 + l15];
    }
    const float* Caf          = (const float*)Caddvp;
    const __hip_bfloat16* Cab = (const __hip_bfloat16*)Caddvp;
    #pragma unroll
    for (int mi = 0; mi < 4; ++mi) {
        #pragma unroll
        for (int r = 0; r < 4; ++r) {
            int m = m0 + wm + mi * 16 + quad * 4 + r;
            if (m < M) {
                #pragma unroll
                for (int ni = 0; ni < 4; ++ni) {
                    int n = wn + ni * 16 + l15;
                    float v = acc[mi][ni][r];
                    if (BIAS) v += bv[ni];
                    if (ADDT == 1) v += Caf[(size_t)m * HD + n];
                    if (ADDT == 2) v += __bfloat162float(Cab[(size_t)m * HD + n]);
                    if (SILU) v = v / (1.f + __expf(-v));
                    if (WF32) Cf[(size_t)m * HD + n] = v;
                    if (WBF)  Cb[(size_t)m * HD + n] = __float2bfloat16(v);
                }
            }
        }
    }
}

// ---------------------------------------------------------------------------
// Fused agg+SiLU+LN+residual. ONE WAVE PER NODE, 2 features per lane (uint
// bf16x2 loads -> 256 B per wave-request). Edge loop unrolled x2 with
// precomputed per-edge {src, norm}. LN via in-wave shfl_xor butterfly.
// ---------------------------------------------------------------------------
__global__ __launch_bounds__(256)
void agg_ln_kernel(const unsigned int* __restrict__ hwu, const float* __restrict__ dis,
                   const int* __restrict__ offs, const int2* __restrict__ csre,
                   const float* __restrict__ cb, const float* __restrict__ lng,
                   const float* __restrict__ lnb, float2* __restrict__ h2,
                   unsigned int* __restrict__ hbfu)
{
    const int lane = threadIdx.x & 63;
    const int n    = blockIdx.x * 4 + (threadIdx.x >> 6);   // NN % 4 == 0

    const float2 cbv = *((const float2*)cb + lane);
    const float  dn  = dis[n];

    // self loop
    float2 sf = unpack_bf2(hwu[(size_t)n * 64 + lane]);
    float acc0 = sf.x * (dn * dn) + cbv.x;
    float acc1 = sf.y * (dn * dn) + cbv.y;

    int e  = offs[n];
    int e1 = offs[n + 1];
    for (; e + 2 <= e1; e += 2) {
        int2 ea = csre[e];
        int2 eb = csre[e + 1];
        unsigned int pa = hwu[(size_t)ea.x * 64 + lane];
        unsigned int pb = hwu[(size_t)eb.x * 64 + lane];
        float wa = __int_as_float(ea.y);
        float wb = __int_as_float(eb.y);
        float2 fa = unpack_bf2(pa);
        float2 fb = unpack_bf2(pb);
        acc0 += wa * fa.x + wb * fb.x;
        acc1 += wa * fa.y + wb * fb.y;
    }
    if (e < e1) {
        int2 ea = csre[e];
        unsigned int pa = hwu[(size_t)ea.x * 64 + lane];
        float wa = __int_as_float(ea.y);
        float2 fa = unpack_bf2(pa);
        acc0 += wa * fa.x;
        acc1 += wa * fa.y;
    }

    // silu
    float v0 = acc0 / (1.f + __expf(-acc0));
    float v1 = acc1 / (1.f + __expf(-acc1));

    // LayerNorm over 128 features, butterfly across 64 lanes
    float s1 = v0 + v1, s2 = v0 * v0 + v1 * v1;
    #pragma unroll
    for (int o = 32; o > 0; o >>= 1) {
        s1 += __shfl_xor(s1, o);
        s2 += __shfl_xor(s2, o);
    }
    float mu  = s1 * (1.f / 128.f);
    float var = s2 * (1.f / 128.f) - mu * mu;
    float rs  = rsqrtf(var + LN_EPS);
    const float2 gv = *((const float2*)lng + lane);
    const float2 bv = *((const float2*)lnb + lane);
    float y0 = (v0 - mu) * rs * gv.x + bv.x;
    float y1 = (v1 - mu) * rs * gv.y + bv.y;

    float2 hv = h2[(size_t)n * 64 + lane];
    hv.x += y0;
    hv.y += y1;
    h2[(size_t)n * 64 + lane]   = hv;
    hbfu[(size_t)n * 64 + lane] = pack_bf2(hv.x, hv.y);
}

// ---------------------------------------------------------------------------
// Graph pooling: offsets via binary search (batch_vec sorted), then mean -> bf16.
// ---------------------------------------------------------------------------
__global__ void goff_kernel(const int* __restrict__ bv, int* __restrict__ goff) {
    int g = blockIdx.x * 256 + threadIdx.x;
    if (g > GG) return;
    int lo = 0, hi = NN;
    while (lo < hi) {
        int mid = (lo + hi) >> 1;
        if (bv[mid] < g) lo = mid + 1; else hi = mid;
    }
    goff[g] = lo;
}

__global__ __launch_bounds__(128)
void pool_kernel(const float* __restrict__ h, const int* __restrict__ goff,
                 __hip_bfloat16* __restrict__ emb)
{
    int g = blockIdx.x;
    int f = threadIdx.x;
    int i0 = goff[g], i1 = goff[g + 1];
    float s = 0.f;
    for (int i = i0; i < i1; ++i) s += h[(size_t)i * HD + f];
    float c = (float)(i1 - i0);
    emb[(size_t)g * HD + f] = __float2bfloat16(s / fmaxf(c, 1.f));
}

// ---------------------------------------------------------------------------
// Final: out[n] = dot(hid[n], w2) + b2  (one wave per node, packed uint loads)
// ---------------------------------------------------------------------------
__global__ __launch_bounds__(256)
void out_kernel(const unsigned int* __restrict__ hidu, const float* __restrict__ w2,
                const float* __restrict__ b2, float* __restrict__ out)
{
    int gw   = (blockIdx.x * 256 + threadIdx.x) >> 6;
    int lane = threadIdx.x & 63;
    if (gw >= NN) return;
    float2 f = unpack_bf2(hidu[(size_t)gw * 64 + lane]);
    float2 w = *((const float2*)w2 + lane);
    float s = f.x * w.x + f.y * w.y;
    #pragma unroll
    for (int o = 32; o > 0; o >>= 1) s += __shfl_down(s, o);
    if (lane == 0) out[gw] = s + b2[0];
}

// ---------------------------------------------------------------------------
// Launcher
// ---------------------------------------------------------------------------
extern "C" void kernel_launch(void* const* d_in, const int* in_sizes, int n_in,
                              void* d_out, int out_size, void* d_ws, size_t ws_size,
                              hipStream_t stream)
{
    const float* x        = (const float*)d_in[0];
    const int*   eidx     = (const int*)d_in[1];
    const int*   batchv   = (const int*)d_in[2];
    const float* in_w     = (const float*)d_in[3];
    const float* in_b     = (const float*)d_in[4];
    const float* conv_w   = (const float*)d_in[5];
    const float* conv_b   = (const float*)d_in[6];
    const float* ln_g     = (const float*)d_in[7];
    const float* ln_b     = (const float*)d_in[8];
    const float* phys_w1  = (const float*)d_in[9];
    const float* phys_b1  = (const float*)d_in[10];
    const float* phys_w2  = (const float*)d_in[11];
    const float* phys_b2  = (const float*)d_in[12];
    const float* head_w1  = (const float*)d_in[13];
    const float* head_b1  = (const float*)d_in[14];
    const float* head_w2  = (const float*)d_in[15];
    const float* head_b2  = (const float*)d_in[16];
    float* out = (float*)d_out;

    const int* esrc = eidx;
    const int* edst = eidx + EE;

    // workspace layout
    char* base = (char*)d_ws;
    size_t off = 0;
    auto alloc = [&](size_t bytes) {
        char* p = base + off;
        off = (off + bytes + 255) & ~(size_t)255;
        return p;
    };
    float*          h      = (float*)alloc((size_t)NN * HD * 4);
    __hip_bfloat16* hbf    = (__hip_bfloat16*)alloc((size_t)NN * HD * 2);
    __hip_bfloat16* bufA   = (__hip_bfloat16*)alloc((size_t)NN * HD * 2);
    float*          dis    = (float*)alloc((size_t)NN * 4);
    int*            degi   = (int*)  alloc((size_t)NN * 4);
    int*            offs   = (int*)  alloc((size_t)(NN + 1) * 4);
    int*            cursor = (int*)  alloc((size_t)NN * 4);
    int2*           csre   = (int2*) alloc((size_t)EE * 8);
    __hip_bfloat16* emb    = (__hip_bfloat16*)alloc((size_t)GG * HD * 2);
    int*            goff   = (int*)  alloc((size_t)(GG + 1) * 4);
    int*            bsums  = (int*)  alloc(1024 * 4);
    __hip_bfloat16* w_in   = (__hip_bfloat16*)alloc(HD * DIN * 2);
    __hip_bfloat16* w_conv = (__hip_bfloat16*)alloc((size_t)NL * HD * HD * 2);
    __hip_bfloat16* w_p1   = (__hip_bfloat16*)alloc(HD * HD * 2);
    __hip_bfloat16* w_p2   = (__hip_bfloat16*)alloc(HD * HD * 2);
    __hip_bfloat16* w_h1a  = (__hip_bfloat16*)alloc(HD * HD * 2);
    __hip_bfloat16* w_h1b  = (__hip_bfloat16*)alloc(HD * HD * 2);
    (void)ws_size; (void)n_in; (void)in_sizes; (void)out_size;

    const int GB = (NN + 127) / 128;   // GEMM grid

    // --- weight conversion (tiny) ---
    cvt_kernel<<<(HD * DIN + 255) / 256, 256, 0, stream>>>(in_w, w_in, HD, DIN, DIN);
    cvt_kernel<<<(NL * HD * HD + 255) / 256, 256, 0, stream>>>(conv_w, w_conv, NL * HD, HD, HD);
    cvt_kernel<<<(HD * HD + 255) / 256, 256, 0, stream>>>(phys_w1, w_p1, HD, HD, HD);
    cvt_kernel<<<(HD * HD + 255) / 256, 256, 0, stream>>>(phys_w2, w_p2, HD, HD, HD);
    cvt_kernel<<<(HD * HD + 255) / 256, 256, 0, stream>>>(head_w1, w_h1a, HD, HD, 2 * HD);
    cvt_kernel<<<(HD * HD + 255) / 256, 256, 0, stream>>>(head_w1 + HD, w_h1b, HD, HD, 2 * HD);

    // --- CSR build ---
    hipMemsetAsync(degi, 0, (size_t)NN * 4, stream);
    hist_kernel<<<(EE + 255) / 256, 256, 0, stream>>>(edst, degi);
    dis_kernel<<<(NN + 255) / 256, 256, 0, stream>>>(degi, dis);
    scan1_kernel<<<NB_SCAN, 256, 0, stream>>>(degi, offs, bsums);
    scan2_kernel<<<1, 1024, 0, stream>>>(bsums);
    scan3_kernel<<<NB_SCAN, 256, 0, stream>>>(offs, bsums, cursor);
    fill_kernel<<<(EE + 255) / 256, 256, 0, stream>>>(esrc, edst, dis, cursor, csre);

    // --- input projection: h = x @ in_w.T + in_b ---
    mgemm<DIN, true, false, true, 0, false, true, true><<<GB, 256, 0, stream>>>(
        x, w_in, in_b, nullptr, nullptr, h, hbf, NN);

    // --- GCN layers ---
    for (int l = 0; l < NL; ++l) {
        mgemm<HD, false, false, false, 0, false, false, true><<<GB, 256, 0, stream>>>(
            hbf, w_conv + (size_t)l * HD * HD, nullptr, nullptr, nullptr, nullptr, bufA, NN);
        agg_ln_kernel<<<NN / 4, 256, 0, stream>>>(
            (const unsigned int*)bufA, dis, offs, csre,
            conv_b + l * HD, ln_g + l * HD, ln_b + l * HD,
            (float2*)h, (unsigned int*)hbf);
    }

    // --- graph mean pooling (bf16 emb) ---
    goff_kernel<<<(GG + 256) / 256, 256, 0, stream>>>(batchv, goff);
    pool_kernel<<<GG, 128, 0, stream>>>(h, goff, emb);

    // --- phys MLP: t1 = silu(h@w1+b1) -> bufA ; hbf = t1@w2 + b2 + hbf (all bf16) ---
    mgemm<HD, false, false, true, 0, true, false, true><<<GB, 256, 0, stream>>>(
        hbf, w_p1, phys_b1, nullptr, nullptr, nullptr, bufA, NN);
    mgemm<HD, false, false, true, 2, false, false, true><<<GB, 256, 0, stream>>>(
        bufA, w_p2, phys_b2, hbf, nullptr, nullptr, hbf, NN);

    // --- head: t2 = P@W1a^T -> bufA ; hid = silu(emb[batch]@W1b^T + t2 + b1) -> hbf ---
    mgemm<HD, false, false, false, 0, false, false, true><<<GB, 256, 0, stream>>>(
        hbf, w_h1a, nullptr, nullptr, nullptr, nullptr, bufA, NN);
    mgemm<HD, false, true, true, 2, true, false, true><<<GB, 256, 0, stream>>>(
        emb, w_h1b, head_b1, bufA, batchv, nullptr, hbf, NN);

    // --- out = hid @ w2 + b2 ---
    out_kernel<<<(NN + 3) / 4, 256, 0, stream>>>((const unsigned int*)hbf, head_w2, head_b2, out);
}